// Round 18
// baseline (538.687 us; speedup 1.0000x reference)
//
#include <hip/hip_runtime.h>
#include <hip/hip_bf16.h>

// Problem constants
#define B_ 32
#define T_ 64
#define E_ 512
#define H_ 512
#define V_ 10000
#define G4 2048   // 4*H

#define NLSTM 64          // recurrence blocks (2 batch-groups x 32 col-slots)
#define NFC   157         // FC consumer blocks: one 64-col n-tile each
#define NTOT  (NLSTM + NFC)

using bf16x8 = __attribute__((ext_vector_type(8))) short;  // 8 bf16 in 4 VGPRs
using f32x4  = __attribute__((ext_vector_type(4))) float;

__device__ inline f32x4 mfma16(bf16x8 a, bf16x8 b, f32x4 c) {
  return __builtin_amdgcn_mfma_f32_16x16x32_bf16(a, b, c, 0, 0, 0);
}

// fp32 -> bf16 round-to-nearest-even, stored as short
__device__ inline short f2bf(float x) {
  unsigned u = __builtin_bit_cast(unsigned, x);
  u = (u + 0x7fffu + ((u >> 16) & 1u)) >> 16;
  return (short)u;
}

// fast transcendental pointwise (bf16-output accuracy is the bar)
__device__ inline float fsigm(float x) {
  return __builtin_amdgcn_rcpf(1.f + __builtin_amdgcn_exp2f(-1.442695040888963f * x));
}
__device__ inline float ftanh(float x) {
  return 1.f - 2.f * __builtin_amdgcn_rcpf(1.f + __builtin_amdgcn_exp2f(2.885390081777927f * x));
}

// Swizzled 16B LDS read (row stride 1024B; byte ^= (row&7)<<4)
__device__ inline bf16x8 lds_ld16B(const short* base, int row, int col) {
  int byte = (row << 10) + (col << 1);
  byte ^= (row & 7) << 4;
  return *(const bf16x8*)((const char*)base + byte);
}

// Cast 8 consecutive fp32 -> bf16x8
__device__ inline bf16x8 cast8(const float* src) {
  float4 f0 = *(const float4*)src;
  float4 f1 = *(const float4*)(src + 4);
  bf16x8 v;
  v[0] = f2bf(f0.x); v[1] = f2bf(f0.y); v[2] = f2bf(f0.z); v[3] = f2bf(f0.w);
  v[4] = f2bf(f1.x); v[5] = f2bf(f1.y); v[6] = f2bf(f1.z); v[7] = f2bf(f1.w);
  return v;
}

// ---------------- SINGLE FUSED DISPATCH ----------------
// 221 co-resident blocks (128KB+ LDS -> 1 block/CU; 221 <= 256 CUs).
//   [0,64):   LSTM recurrence (R16 structure). Stages W_hh + W_ih 64-row
//             slices in LDS (128KB) + caption indices (4KB). Per step:
//             gates_x B-frag reads features/embed DIRECTLY (cast8) — no xs
//             buffer, no prep kernel. 16 MFMA pre-poll, poll peers' flags,
//             16 MFMA h-part, pointwise in-register, agent h-store + flag +
//             cnt[t].
//   [64,221): FC consumers (R15/R16 structure: fc_W cast into LDS once,
//             wave-0 polls cnt[t]==64, waves 1-3 spin on LDS tready).
// flags layout (ints): [0..63] lstm flags; [256..319] cnt[t].

__global__ __launch_bounds__(256) void fused_kernel(const float* __restrict__ WhhF,
                                                    const float* __restrict__ WihF,
                                                    const float* __restrict__ b_ih,
                                                    const float* __restrict__ b_hh,
                                                    const float* __restrict__ features,
                                                    const int* __restrict__ captions,
                                                    const float* __restrict__ embed,
                                                    short* __restrict__ hs,   // [T][B][H]
                                                    int* __restrict__ flags,
                                                    const float* __restrict__ fcWF,
                                                    const float* __restrict__ fcbias,
                                                    float* __restrict__ out) {
  __shared__ short Wlds[2 * 64 * 512];   // 128 KB swizzled (lstm: Whh+Wih; FC: fcW in [0])
  __shared__ int cap_lds[16][64];        // lstm: caption idx per (group-row, t)
  __shared__ int tready;                 // FC broadcast
  const int tid = threadIdx.x;
  int* const cnt = flags + 256;

  if (blockIdx.x < NLSTM) {
    // ================= LSTM recurrence role ==============
    const int blk  = blockIdx.x;
    const int bg   = blk >> 5;          // batch group 0/1
    const int slot = blk & 31;          // h-column slot
    const int hc0  = slot * 16;
    int* const gflags = flags + bg * 32;

    // stage W_hh (region 0) + W_ih (region 1) slices, fp32->bf16, swizzled
    for (int i = tid * 8; i < 2 * 64 * 512; i += 256 * 8) {
      int region = i >> 15;             // 0: Whh, 1: Wih
      int local  = i & 32767;
      int gc = local >> 9;
      int k  = local & 511;
      int g  = gc >> 4, c = gc & 15;
      const float* src = (region ? WihF : WhhF) + (size_t)(g * 512 + hc0 + c) * 512 + k;
      bf16x8 v = cast8(src);
      int byte = ((local * 2) ^ ((gc & 7) << 4)) + (region << 16);
      *(bf16x8*)((char*)Wlds + byte) = v;
    }
    // stage caption indices: cap_lds[b][t] = captions[(bg*16+b)*T + (t-1)], t>=1
    for (int i = tid; i < 16 * 63; i += 256) {
      int b = i / 63;
      int t = i - b * 63 + 1;
      cap_lds[b][t] = captions[(bg * 16 + b) * T_ + (t - 1)];
    }
    __syncthreads();
    if (tid >= 64) return;   // waves 1-3 done

    const short* WB = Wlds + 64 * 512;  // W_ih region
    const int lane = tid;
    const int lr  = lane & 15;
    const int ko  = (lane >> 4) << 3;
    const int cr  = (lane >> 4) << 2;
    const int cc  = lane & 15;
    const int bat = bg * 16 + cc;       // batch of this lane's output cells
    const int brow = bg * 16 + lr;      // batch row for B-frags (x and h)

    // per-lane gate biases: (b_ih+b_hh)[g*512 + hc0+cr .. +4)
    float4 bb0, bb1, bb2, bb3;
    {
      float4 i0 = *(const float4*)&b_ih[0 * 512 + hc0 + cr];
      float4 h0 = *(const float4*)&b_hh[0 * 512 + hc0 + cr];
      float4 i1 = *(const float4*)&b_ih[1 * 512 + hc0 + cr];
      float4 h1 = *(const float4*)&b_hh[1 * 512 + hc0 + cr];
      float4 i2 = *(const float4*)&b_ih[2 * 512 + hc0 + cr];
      float4 h2 = *(const float4*)&b_hh[2 * 512 + hc0 + cr];
      float4 i3 = *(const float4*)&b_ih[3 * 512 + hc0 + cr];
      float4 h3 = *(const float4*)&b_hh[3 * 512 + hc0 + cr];
      bb0 = make_float4(i0.x + h0.x, i0.y + h0.y, i0.z + h0.z, i0.w + h0.w);
      bb1 = make_float4(i1.x + h1.x, i1.y + h1.y, i1.z + h1.z, i1.w + h1.w);
      bb2 = make_float4(i2.x + h2.x, i2.y + h2.y, i2.z + h2.z, i2.w + h2.w);
      bb3 = make_float4(i3.x + h3.x, i3.y + h3.y, i3.z + h3.z, i3.w + h3.w);
    }

    float cst[4] = {0.f, 0.f, 0.f, 0.f};

    for (int t = 0; t < T_; ++t) {
      f32x4 a0 = {}, a1 = {}, a2 = {}, a3 = {};
      // ---- gates_x: B-frag direct from features/embed (fp32, cast8) -------
      {
        const float* xrow = (t == 0)
            ? features + (size_t)brow * 512
            : embed + (size_t)cap_lds[lr][t] * 512;
#pragma unroll
        for (int kk = 0; kk < 512; kk += 32) {
          bf16x8 xb = cast8(xrow + kk + ko);
          bf16x8 w0 = lds_ld16B(WB,      lr, kk + ko);
          bf16x8 w1 = lds_ld16B(WB, 16 + lr, kk + ko);
          bf16x8 w2 = lds_ld16B(WB, 32 + lr, kk + ko);
          bf16x8 w3 = lds_ld16B(WB, 48 + lr, kk + ko);
          a0 = mfma16(w0, xb, a0);
          a1 = mfma16(w1, xb, a1);
          a2 = mfma16(w2, xb, a2);
          a3 = mfma16(w3, xb, a3);
        }
      }
      if (t > 0) {
        // ---- wait for peers' h[t-1], then accumulate h-part ----
        const int* fp = gflags + (lane & 31);
        for (;;) {
          int fl = __hip_atomic_load(fp, __ATOMIC_RELAXED, __HIP_MEMORY_SCOPE_AGENT);
          if (__all(fl >= t)) break;
        }
        asm volatile("" ::: "memory");
        const short* Ap = hs + (size_t)(t - 1) * (B_ * H_) + brow * 512 + ko;
#pragma unroll
        for (int kk = 0; kk < 512; kk += 32) {
          bf16x8 hb = *(const bf16x8*)(Ap + kk);
          bf16x8 w0 = lds_ld16B(Wlds,      lr, kk + ko);
          bf16x8 w1 = lds_ld16B(Wlds, 16 + lr, kk + ko);
          bf16x8 w2 = lds_ld16B(Wlds, 32 + lr, kk + ko);
          bf16x8 w3 = lds_ld16B(Wlds, 48 + lr, kk + ko);
          a0 = mfma16(w0, hb, a0);
          a1 = mfma16(w1, hb, a1);
          a2 = mfma16(w2, hb, a2);
          a3 = mfma16(w3, hb, a3);
        }
      }
      // ---- pointwise LSTM cell, fully in-register ----
      unsigned long long hpack = 0;
#pragma unroll
      for (int j = 0; j < 4; ++j) {
        float iv = fsigm(a0[j] + ((const float*)&bb0)[j]);
        float fv = fsigm(a1[j] + ((const float*)&bb1)[j]);
        float gv = ftanh(a2[j] + ((const float*)&bb2)[j]);
        float ov = fsigm(a3[j] + ((const float*)&bb3)[j]);
        float cv = fv * cst[j] + iv * gv;
        cst[j] = cv;
        float hv = ov * ftanh(cv);
        hpack |= (unsigned long long)(unsigned short)f2bf(hv) << (16 * j);
      }
      __hip_atomic_store(
          (unsigned long long*)(hs + (size_t)t * (B_ * H_) + bat * 512 + hc0 + cr),
          hpack, __ATOMIC_RELAXED, __HIP_MEMORY_SCOPE_AGENT);
      // drain own store; flag lstm peers (t<63) + bump per-t counter (all t)
      asm volatile("s_waitcnt vmcnt(0)" ::: "memory");
      if (lane == 0) {
        if (t < T_ - 1)
          __hip_atomic_store(gflags + slot, t + 1, __ATOMIC_RELAXED,
                             __HIP_MEMORY_SCOPE_AGENT);
        __hip_atomic_fetch_add(cnt + t, 1, __ATOMIC_RELAXED,
                               __HIP_MEMORY_SCOPE_AGENT);   // fire-and-forget
      }
    }
  } else {
    // ================= FC consumer role (n-major, fc_W cast into LDS) ======
    const int fblk = blockIdx.x - NLSTM;   // 0..156
    const int n0   = fblk * 64;            // this block's 64 output cols
    const int lane = tid & 63;
    const int wv   = tid >> 6;
    const int lr   = lane & 15;
    const int ko   = (lane >> 4) << 3;

    if (tid == 0)
      __hip_atomic_store(&tready, 0, __ATOMIC_RELAXED, __HIP_MEMORY_SCOPE_WORKGROUP);

    for (int i = tid * 8; i < 64 * 512; i += 256 * 8) {
      int gc = i >> 9;
      int k  = i & 511;
      int nr = n0 + gc; if (nr >= V_) nr = V_ - 1;
      bf16x8 v = cast8(fcWF + (size_t)nr * 512 + k);
      int byte = (i * 2) ^ ((gc & 7) << 4);
      *(bf16x8*)((char*)Wlds + byte) = v;
    }
    __syncthreads();   // covers tready init + Wlds staging

    const int cr = (lane >> 4) * 4, cc = lane & 15;
    const int colw = n0 + wv * 16 + cc;
    const bool wok = colw < V_;
    const float bias = wok ? fcbias[colw] : 0.f;

    for (int t = 0; t < T_; ++t) {
      if (wv == 0) {
        // single poller wave reads ONE word: cnt[t] == 64
        for (;;) {
          int c = __hip_atomic_load(cnt + t, __ATOMIC_RELAXED,
                                    __HIP_MEMORY_SCOPE_AGENT);
          if (c >= NLSTM) break;
          __builtin_amdgcn_s_sleep(32);
        }
        __hip_atomic_store(&tready, t + 1, __ATOMIC_RELAXED,
                           __HIP_MEMORY_SCOPE_WORKGROUP);
      } else {
        while (__hip_atomic_load(&tready, __ATOMIC_RELAXED,
                                 __HIP_MEMORY_SCOPE_WORKGROUP) < t + 1)
          __builtin_amdgcn_s_sleep(2);
      }
      asm volatile("" ::: "memory");
      const short* Ap = hs + (size_t)t * (B_ * H_) + lr * 512 + ko;
      f32x4 acc0 = {}, acc1 = {};
#pragma unroll
      for (int k = 0; k < 512; k += 32) {
        bf16x8 a0 = *(const bf16x8*)(Ap + k);
        bf16x8 a1 = *(const bf16x8*)(Ap + 16 * 512 + k);
        bf16x8 b  = lds_ld16B(Wlds, wv * 16 + lr, k + ko);
        acc0 = mfma16(a0, b, acc0);
        acc1 = mfma16(a1, b, acc1);
      }
      if (wok) {
#pragma unroll
        for (int j = 0; j < 4; ++j) {
          out[(size_t)(cr + j) * (T_ * V_) + t * V_ + colw]      = acc0[j] + bias;
          out[(size_t)(16 + cr + j) * (T_ * V_) + t * V_ + colw] = acc1[j] + bias;
        }
      }
    }
  }
}

// ---------------- launch ----------------

extern "C" void kernel_launch(void* const* d_in, const int* in_sizes, int n_in,
                              void* d_out, int out_size, void* d_ws, size_t ws_size,
                              hipStream_t stream) {
  const float* features = (const float*)d_in[0];
  const int*   captions = (const int*)d_in[1];
  const float* embed    = (const float*)d_in[3];
  const float* W_ih     = (const float*)d_in[4];
  const float* W_hh     = (const float*)d_in[5];
  const float* b_ih     = (const float*)d_in[6];
  const float* b_hh     = (const float*)d_in[7];
  const float* fc_W     = (const float*)d_in[8];
  const float* fc_b     = (const float*)d_in[9];
  float* out = (float*)d_out;

  char* ws = (char*)d_ws;
  size_t off = 0;
  auto alloc = [&](size_t bytes) -> void* {
    off = (off + 255) & ~(size_t)255;
    void* p = ws + off;
    off += bytes;
    return p;
  };
  int*   flags = (int*)  alloc(4096);   // [0..63] flags, [256..319] cnt
  short* hs    = (short*)alloc((size_t)T_ * B_ * H_ * 2);

  (void)hipMemsetAsync(flags, 0, 4096, stream);
  fused_kernel<<<NTOT, 256, 0, stream>>>(W_hh, W_ih, b_ih, b_hh,
                                         features, captions, embed,
                                         hs, flags, fc_W, fc_b, out);
}

// Round 19
// 277.081 us; speedup vs baseline: 1.9442x; 1.9442x over previous
//
#include <hip/hip_runtime.h>
#include <hip/hip_bf16.h>

// Problem constants
#define B_ 32
#define T_ 64
#define E_ 512
#define H_ 512
#define V_ 10000
#define G4 2048   // 4*H

#define NLSTM 64          // recurrence blocks (2 batch-groups x 32 col-slots)
#define NFC   157         // FC consumer blocks: one 64-col n-tile each
#define NTOT  (NLSTM + NFC)

using bf16x8 = __attribute__((ext_vector_type(8))) short;  // 8 bf16 in 4 VGPRs
using f32x4  = __attribute__((ext_vector_type(4))) float;

__device__ inline f32x4 mfma16(bf16x8 a, bf16x8 b, f32x4 c) {
  return __builtin_amdgcn_mfma_f32_16x16x32_bf16(a, b, c, 0, 0, 0);
}

// fp32 -> bf16 round-to-nearest-even, stored as short
__device__ inline short f2bf(float x) {
  unsigned u = __builtin_bit_cast(unsigned, x);
  u = (u + 0x7fffu + ((u >> 16) & 1u)) >> 16;
  return (short)u;
}

// fast transcendental pointwise (bf16-output accuracy is the bar)
__device__ inline float fsigm(float x) {
  return __builtin_amdgcn_rcpf(1.f + __builtin_amdgcn_exp2f(-1.442695040888963f * x));
}
__device__ inline float ftanh(float x) {
  return 1.f - 2.f * __builtin_amdgcn_rcpf(1.f + __builtin_amdgcn_exp2f(2.885390081777927f * x));
}

// Swizzled 16B LDS read: row stride 1024B, byte ^= (row&7)<<4 kills the
// 16-way bank conflict of the row-major [*][512] bf16 layout (guide G4).
__device__ inline bf16x8 lds_ld16B(const short* base, int row, int col) {
  int byte = (row << 10) + (col << 1);
  byte ^= (row & 7) << 4;
  return *(const bf16x8*)((const char*)base + byte);
}

// Stage 8 fp32 -> bf16x8 (for in-kernel weight casting)
__device__ inline bf16x8 cast8(const float* src) {
  float4 f0 = *(const float4*)src;
  float4 f1 = *(const float4*)(src + 4);
  bf16x8 v;
  v[0] = f2bf(f0.x); v[1] = f2bf(f0.y); v[2] = f2bf(f0.z); v[3] = f2bf(f0.w);
  v[4] = f2bf(f1.x); v[5] = f2bf(f1.y); v[6] = f2bf(f1.z); v[7] = f2bf(f1.w);
  return v;
}

// ---------------- prep kernel: bsum + xs only ----------------
// xs MUST be materialized (bf16): the lstm role's pre-poll x-MFMA loads it,
// and the poll's implicit vmcnt drain makes those loads part of the critical
// path. A hot 32KB bf16 L2 panel is cheap; direct fp32 embed gathers are not
// (R18 regression: +6 us/step).

__global__ void prep_kernel(const float* __restrict__ b_ih, const float* __restrict__ b_hh,
                            const float* __restrict__ features, const int* __restrict__ captions,
                            const float* __restrict__ embed,
                            float* __restrict__ bsum, short* __restrict__ xs) {
  int i = blockIdx.x * blockDim.x + threadIdx.x;
  int stride = gridDim.x * blockDim.x;
  const int NA = G4;
  const int NB = NA + T_ * B_ * E_;
  for (; i < NB; i += stride) {
    if (i < NA) {
      bsum[i] = b_ih[i] + b_hh[i];
    } else {
      int j = i - NA;                 // [t][b][e]
      int t = j / (B_ * E_);
      int r = j - t * (B_ * E_);
      int b = r >> 9;
      int e = r & 511;
      float v;
      if (t == 0) v = features[b * E_ + e];
      else        v = embed[captions[b * T_ + (t - 1)] * E_ + e];
      xs[j] = f2bf(v);
    }
  }
}

// ---------------- FUSED: recurrence (with inline Gx) + FC consumer ---------
// 221 co-resident blocks (128KB LDS -> 1 block/CU; 221 <= 256 CUs).
//   [0,64):   LSTM recurrence. Stages BOTH W_hh and W_ih 64-row slices in
//             LDS (128KB). Per step: gates_x = xs[t] @ W_ih_slice (16 MFMA,
//             issued BEFORE the flag poll -> hides under the wait), poll,
//             gates += h[t-1] @ W_hh_slice (16 MFMA), pointwise, h-store +
//             flag + cnt[t]. NO Gx buffer, NO cross-block Gx dependency.
//   [64,221): FC consumers (fc_W cast into LDS once, wave-0 polls
//             cnt[t]==64, waves 1-3 spin on LDS tready).

__global__ __launch_bounds__(256) void fused_kernel(const float* __restrict__ WhhF,
                                                    const float* __restrict__ WihF,
                                                    const float* __restrict__ bsum,
                                                    const short* __restrict__ xs, // [T][B][E]
                                                    short* __restrict__ hs,       // [T][B][H]
                                                    int* __restrict__ flags,
                                                    const float* __restrict__ fcWF,
                                                    const float* __restrict__ fcbias,
                                                    float* __restrict__ out) {
  __shared__ short Wlds[2 * 64 * 512];   // 128 KB swizzled (lstm: Whh+Wih; FC: fcW in [0])
  __shared__ int tready;                 // FC role broadcast
  const int tid = threadIdx.x;
  int* const cnt = flags + 256;

  if (blockIdx.x < NLSTM) {
    // ================= LSTM recurrence role ==============
    const int blk  = blockIdx.x;
    const int bg   = blk >> 5;          // batch group 0/1
    const int slot = blk & 31;          // h-column slot
    const int hc0  = slot * 16;
    int* const gflags = flags + bg * 32;

    // stage W_hh (region 0) + W_ih (region 1) slices, fp32->bf16, swizzled
    for (int i = tid * 8; i < 2 * 64 * 512; i += 256 * 8) {
      int region = i >> 15;             // 0: Whh, 1: Wih
      int local  = i & 32767;
      int gc = local >> 9;
      int k  = local & 511;
      int g  = gc >> 4, c = gc & 15;
      const float* src = (region ? WihF : WhhF) + (size_t)(g * 512 + hc0 + c) * 512 + k;
      bf16x8 v = cast8(src);
      int byte = ((local * 2) ^ ((gc & 7) << 4)) + (region << 16);
      *(bf16x8*)((char*)Wlds + byte) = v;
    }
    __syncthreads();
    if (tid >= 64) return;   // waves 1-3 done

    const short* WB = Wlds + 64 * 512;  // W_ih region
    const int lane = tid;
    const int lr  = lane & 15;
    const int ko  = (lane >> 4) << 3;
    const int cr  = (lane >> 4) << 2;
    const int cc  = lane & 15;
    const int bat = bg * 16 + cc;       // batch of this lane's output cells
    const int brow = bg * 16 + lr;      // batch row for B-frags (xs and h)

    // per-lane gate biases: bsum[g*512 + hc0+cr .. +4)
    float4 bb0 = *(const float4*)&bsum[0 * 512 + hc0 + cr];
    float4 bb1 = *(const float4*)&bsum[1 * 512 + hc0 + cr];
    float4 bb2 = *(const float4*)&bsum[2 * 512 + hc0 + cr];
    float4 bb3 = *(const float4*)&bsum[3 * 512 + hc0 + cr];

    float cst[4] = {0.f, 0.f, 0.f, 0.f};

    for (int t = 0; t < T_; ++t) {
      f32x4 a0 = {}, a1 = {}, a2 = {}, a3 = {};
      // ---- gates_x = xs[t] @ W_ih^T : independent of h, issued pre-poll ----
      {
        const short* Ax = xs + ((size_t)t * B_ + brow) * 512 + ko;
#pragma unroll
        for (int kk = 0; kk < 512; kk += 32) {
          bf16x8 xb = *(const bf16x8*)(Ax + kk);
          bf16x8 w0 = lds_ld16B(WB,      lr, kk + ko);
          bf16x8 w1 = lds_ld16B(WB, 16 + lr, kk + ko);
          bf16x8 w2 = lds_ld16B(WB, 32 + lr, kk + ko);
          bf16x8 w3 = lds_ld16B(WB, 48 + lr, kk + ko);
          a0 = mfma16(w0, xb, a0);
          a1 = mfma16(w1, xb, a1);
          a2 = mfma16(w2, xb, a2);
          a3 = mfma16(w3, xb, a3);
        }
      }
      if (t > 0) {
        // ---- wait for peers' h[t-1], then accumulate h-part ----
        const int* fp = gflags + (lane & 31);
        for (;;) {
          int fl = __hip_atomic_load(fp, __ATOMIC_RELAXED, __HIP_MEMORY_SCOPE_AGENT);
          if (__all(fl >= t)) break;
        }
        asm volatile("" ::: "memory");
        const short* Ap = hs + (size_t)(t - 1) * (B_ * H_) + brow * 512 + ko;
#pragma unroll
        for (int kk = 0; kk < 512; kk += 32) {
          bf16x8 hb = *(const bf16x8*)(Ap + kk);
          bf16x8 w0 = lds_ld16B(Wlds,      lr, kk + ko);
          bf16x8 w1 = lds_ld16B(Wlds, 16 + lr, kk + ko);
          bf16x8 w2 = lds_ld16B(Wlds, 32 + lr, kk + ko);
          bf16x8 w3 = lds_ld16B(Wlds, 48 + lr, kk + ko);
          a0 = mfma16(w0, hb, a0);
          a1 = mfma16(w1, hb, a1);
          a2 = mfma16(w2, hb, a2);
          a3 = mfma16(w3, hb, a3);
        }
      }
      // ---- pointwise LSTM cell, fully in-register ----
      unsigned long long hpack = 0;
#pragma unroll
      for (int j = 0; j < 4; ++j) {
        float iv = fsigm(a0[j] + ((const float*)&bb0)[j]);
        float fv = fsigm(a1[j] + ((const float*)&bb1)[j]);
        float gv = ftanh(a2[j] + ((const float*)&bb2)[j]);
        float ov = fsigm(a3[j] + ((const float*)&bb3)[j]);
        float cv = fv * cst[j] + iv * gv;
        cst[j] = cv;
        float hv = ov * ftanh(cv);
        hpack |= (unsigned long long)(unsigned short)f2bf(hv) << (16 * j);
      }
      __hip_atomic_store(
          (unsigned long long*)(hs + (size_t)t * (B_ * H_) + bat * 512 + hc0 + cr),
          hpack, __ATOMIC_RELAXED, __HIP_MEMORY_SCOPE_AGENT);
      // drain own store; flag lstm peers (t<63) + bump per-t counter (all t)
      asm volatile("s_waitcnt vmcnt(0)" ::: "memory");
      if (lane == 0) {
        if (t < T_ - 1)
          __hip_atomic_store(gflags + slot, t + 1, __ATOMIC_RELAXED,
                             __HIP_MEMORY_SCOPE_AGENT);
        __hip_atomic_fetch_add(cnt + t, 1, __ATOMIC_RELAXED,
                               __HIP_MEMORY_SCOPE_AGENT);   // fire-and-forget
      }
    }
  } else {
    // ================= FC consumer role (n-major, fc_W cast into LDS) ======
    const int fblk = blockIdx.x - NLSTM;   // 0..156
    const int n0   = fblk * 64;            // this block's 64 output cols
    const int lane = tid & 63;
    const int wv   = tid >> 6;
    const int lr   = lane & 15;
    const int ko   = (lane >> 4) << 3;

    if (tid == 0)
      __hip_atomic_store(&tready, 0, __ATOMIC_RELAXED, __HIP_MEMORY_SCOPE_WORKGROUP);

    for (int i = tid * 8; i < 64 * 512; i += 256 * 8) {
      int gc = i >> 9;
      int k  = i & 511;
      int nr = n0 + gc; if (nr >= V_) nr = V_ - 1;
      bf16x8 v = cast8(fcWF + (size_t)nr * 512 + k);
      int byte = (i * 2) ^ ((gc & 7) << 4);
      *(bf16x8*)((char*)Wlds + byte) = v;
    }
    __syncthreads();   // covers tready init + Wlds staging

    const int cr = (lane >> 4) * 4, cc = lane & 15;
    const int colw = n0 + wv * 16 + cc;
    const bool wok = colw < V_;
    const float bias = wok ? fcbias[colw] : 0.f;

    for (int t = 0; t < T_; ++t) {
      if (wv == 0) {
        // single poller wave reads ONE word: cnt[t] == 64
        for (;;) {
          int c = __hip_atomic_load(cnt + t, __ATOMIC_RELAXED,
                                    __HIP_MEMORY_SCOPE_AGENT);
          if (c >= NLSTM) break;
          __builtin_amdgcn_s_sleep(32);
        }
        __hip_atomic_store(&tready, t + 1, __ATOMIC_RELAXED,
                           __HIP_MEMORY_SCOPE_WORKGROUP);
      } else {
        while (__hip_atomic_load(&tready, __ATOMIC_RELAXED,
                                 __HIP_MEMORY_SCOPE_WORKGROUP) < t + 1)
          __builtin_amdgcn_s_sleep(2);
      }
      asm volatile("" ::: "memory");
      const short* Ap = hs + (size_t)t * (B_ * H_) + lr * 512 + ko;
      f32x4 acc0 = {}, acc1 = {};
#pragma unroll
      for (int k = 0; k < 512; k += 32) {
        bf16x8 a0 = *(const bf16x8*)(Ap + k);
        bf16x8 a1 = *(const bf16x8*)(Ap + 16 * 512 + k);
        bf16x8 b  = lds_ld16B(Wlds, wv * 16 + lr, k + ko);
        acc0 = mfma16(a0, b, acc0);
        acc1 = mfma16(a1, b, acc1);
      }
      if (wok) {
#pragma unroll
        for (int j = 0; j < 4; ++j) {
          out[(size_t)(cr + j) * (T_ * V_) + t * V_ + colw]      = acc0[j] + bias;
          out[(size_t)(16 + cr + j) * (T_ * V_) + t * V_ + colw] = acc1[j] + bias;
        }
      }
    }
  }
}

// ---------------- launch ----------------

extern "C" void kernel_launch(void* const* d_in, const int* in_sizes, int n_in,
                              void* d_out, int out_size, void* d_ws, size_t ws_size,
                              hipStream_t stream) {
  const float* features = (const float*)d_in[0];
  const int*   captions = (const int*)d_in[1];
  const float* embed    = (const float*)d_in[3];
  const float* W_ih     = (const float*)d_in[4];
  const float* W_hh     = (const float*)d_in[5];
  const float* b_ih     = (const float*)d_in[6];
  const float* b_hh     = (const float*)d_in[7];
  const float* fc_W     = (const float*)d_in[8];
  const float* fc_b     = (const float*)d_in[9];
  float* out = (float*)d_out;

  char* ws = (char*)d_ws;
  size_t off = 0;
  auto alloc = [&](size_t bytes) -> void* {
    off = (off + 255) & ~(size_t)255;
    void* p = ws + off;
    off += bytes;
    return p;
  };
  int*      flags = (int*)  alloc(4096);   // [0..63] flags, [256..319] cnt
  float*    bsum  = (float*)alloc((size_t)G4 * 4);
  short*    xs    = (short*)alloc((size_t)T_ * B_ * E_ * 2);
  short*    hs    = (short*)alloc((size_t)T_ * B_ * H_ * 2);

  (void)hipMemsetAsync(flags, 0, 4096, stream);
  prep_kernel<<<1024, 256, 0, stream>>>(b_ih, b_hh, features, captions, embed,
                                        bsum, xs);
  fused_kernel<<<NTOT, 256, 0, stream>>>(W_hh, W_ih, bsum, xs, hs, flags,
                                         fc_W, fc_b, out);
}

// Round 20
// 276.283 us; speedup vs baseline: 1.9498x; 1.0029x over previous
//
#include <hip/hip_runtime.h>
#include <hip/hip_bf16.h>

// Problem constants
#define B_ 32
#define T_ 64
#define E_ 512
#define H_ 512
#define V_ 10000
#define G4 2048   // 4*H

#define NLSTM 64          // recurrence blocks (2 batch-groups x 32 col-slots)
#define NFC   157         // FC consumer blocks: one 64-col n-tile each
#define NTOT  (NLSTM + NFC)

using bf16x8 = __attribute__((ext_vector_type(8))) short;  // 8 bf16 in 4 VGPRs
using f32x4  = __attribute__((ext_vector_type(4))) float;

__device__ inline f32x4 mfma16(bf16x8 a, bf16x8 b, f32x4 c) {
  return __builtin_amdgcn_mfma_f32_16x16x32_bf16(a, b, c, 0, 0, 0);
}

// fp32 -> bf16 round-to-nearest-even, stored as short
__device__ inline short f2bf(float x) {
  unsigned u = __builtin_bit_cast(unsigned, x);
  u = (u + 0x7fffu + ((u >> 16) & 1u)) >> 16;
  return (short)u;
}

// fast transcendental pointwise (bf16-output accuracy is the bar)
__device__ inline float fsigm(float x) {
  return __builtin_amdgcn_rcpf(1.f + __builtin_amdgcn_exp2f(-1.442695040888963f * x));
}
__device__ inline float ftanh(float x) {
  return 1.f - 2.f * __builtin_amdgcn_rcpf(1.f + __builtin_amdgcn_exp2f(2.885390081777927f * x));
}

// Swizzled 16B LDS read: row stride 1024B, byte ^= (row&7)<<4 kills the
// 16-way bank conflict of the row-major [*][512] bf16 layout (guide G4).
__device__ inline bf16x8 lds_ld16B(const short* base, int row, int col) {
  int byte = (row << 10) + (col << 1);
  byte ^= (row & 7) << 4;
  return *(const bf16x8*)((const char*)base + byte);
}

// Stage 8 fp32 -> bf16x8 (for in-kernel weight casting)
__device__ inline bf16x8 cast8(const float* src) {
  float4 f0 = *(const float4*)src;
  float4 f1 = *(const float4*)(src + 4);
  bf16x8 v;
  v[0] = f2bf(f0.x); v[1] = f2bf(f0.y); v[2] = f2bf(f0.z); v[3] = f2bf(f0.w);
  v[4] = f2bf(f1.x); v[5] = f2bf(f1.y); v[6] = f2bf(f1.z); v[7] = f2bf(f1.w);
  return v;
}

// ---------------- prep kernel: bsum + xs only ----------------
// xs MUST be materialized (bf16): the lstm role's pre-poll x-MFMA loads it,
// and the poll's implicit vmcnt drain makes those loads part of the critical
// path (R18 regression: direct fp32 embed gathers cost +6 us/step).

__global__ void prep_kernel(const float* __restrict__ b_ih, const float* __restrict__ b_hh,
                            const float* __restrict__ features, const int* __restrict__ captions,
                            const float* __restrict__ embed,
                            float* __restrict__ bsum, short* __restrict__ xs) {
  int i = blockIdx.x * blockDim.x + threadIdx.x;
  int stride = gridDim.x * blockDim.x;
  const int NA = G4;
  const int NB = NA + T_ * B_ * E_;
  for (; i < NB; i += stride) {
    if (i < NA) {
      bsum[i] = b_ih[i] + b_hh[i];
    } else {
      int j = i - NA;                 // [t][b][e]
      int t = j / (B_ * E_);
      int r = j - t * (B_ * E_);
      int b = r >> 9;
      int e = r & 511;
      float v;
      if (t == 0) v = features[b * E_ + e];
      else        v = embed[captions[b * T_ + (t - 1)] * E_ + e];
      xs[j] = f2bf(v);
    }
  }
}

// ---------------- FUSED: recurrence (with inline Gx) + FC consumer ---------
// 221 co-resident blocks (128KB LDS -> 1 block/CU; 221 <= 256 CUs).
//   [0,64):   LSTM recurrence (R16 structure) + FLAG OFFLOAD: vmcnt is
//             in-order, so lane-0's fire-and-forget flag/cnt stores used to
//             delay the NEXT step's poll (its waitcnt drains them, ~700cy).
//             Now wave 0 only drains its h-store and bumps an LDS mailbox;
//             wave 1 (lane 0) spins on the mailbox via LDS (lgkmcnt — does
//             NOT wait on vmcnt) and issues gflag/cnt stores, never draining
//             them. Wave 0's loop has exactly one vmem serialization point.
//   [64,221): FC consumers (fc_W cast into LDS once, wave-0 polls
//             cnt[t]==64, waves 1-3 spin on LDS tready).
// Deadlock audit: wave0 bumps hmail unconditionally each t; wave1 spins only
// on hmail; peer wave0s spin on flags raised by peer wave1s -> acyclic.

__global__ __launch_bounds__(256) void fused_kernel(const float* __restrict__ WhhF,
                                                    const float* __restrict__ WihF,
                                                    const float* __restrict__ bsum,
                                                    const short* __restrict__ xs, // [T][B][E]
                                                    short* __restrict__ hs,       // [T][B][H]
                                                    int* __restrict__ flags,
                                                    const float* __restrict__ fcWF,
                                                    const float* __restrict__ fcbias,
                                                    float* __restrict__ out) {
  __shared__ short Wlds[2 * 64 * 512];   // 128 KB swizzled (lstm: Whh+Wih; FC: fcW in [0])
  __shared__ int tready;                 // FC role broadcast
  __shared__ int hmail;                  // lstm: wave0 -> wave1 mailbox
  const int tid = threadIdx.x;
  int* const cnt = flags + 256;

  if (blockIdx.x < NLSTM) {
    // ================= LSTM recurrence role ==============
    const int blk  = blockIdx.x;
    const int bg   = blk >> 5;          // batch group 0/1
    const int slot = blk & 31;          // h-column slot
    const int hc0  = slot * 16;
    int* const gflags = flags + bg * 32;

    if (tid == 0) hmail = 0;
    // stage W_hh (region 0) + W_ih (region 1) slices, fp32->bf16, swizzled
    for (int i = tid * 8; i < 2 * 64 * 512; i += 256 * 8) {
      int region = i >> 15;             // 0: Whh, 1: Wih
      int local  = i & 32767;
      int gc = local >> 9;
      int k  = local & 511;
      int g  = gc >> 4, c = gc & 15;
      const float* src = (region ? WihF : WhhF) + (size_t)(g * 512 + hc0 + c) * 512 + k;
      bf16x8 v = cast8(src);
      int byte = ((local * 2) ^ ((gc & 7) << 4)) + (region << 16);
      *(bf16x8*)((char*)Wlds + byte) = v;
    }
    __syncthreads();
    const int wv   = tid >> 6;
    const int lane = tid & 63;
    if (wv >= 2) return;   // waves 2,3 done

    if (wv == 1) {
      // ---- flag-raiser wave: lane 0 only ----
      if (lane != 0) return;
      for (int t = 0; t < T_; ++t) {
        while (__hip_atomic_load(&hmail, __ATOMIC_RELAXED,
                                 __HIP_MEMORY_SCOPE_WORKGROUP) < t + 1)
          __builtin_amdgcn_s_sleep(1);
        if (t < T_ - 1)
          __hip_atomic_store(gflags + slot, t + 1, __ATOMIC_RELAXED,
                             __HIP_MEMORY_SCOPE_AGENT);
        __hip_atomic_fetch_add(cnt + t, 1, __ATOMIC_RELAXED,
                               __HIP_MEMORY_SCOPE_AGENT);
        // fire-and-forget: never drained — LDS spin above uses lgkmcnt only
      }
      return;
    }

    // ---- wave 0: compute wave ----
    const short* WB = Wlds + 64 * 512;  // W_ih region
    const int lr  = lane & 15;
    const int ko  = (lane >> 4) << 3;
    const int cr  = (lane >> 4) << 2;
    const int cc  = lane & 15;
    const int bat = bg * 16 + cc;       // batch of this lane's output cells
    const int brow = bg * 16 + lr;      // batch row for B-frags (xs and h)

    // per-lane gate biases: bsum[g*512 + hc0+cr .. +4)
    float4 bb0 = *(const float4*)&bsum[0 * 512 + hc0 + cr];
    float4 bb1 = *(const float4*)&bsum[1 * 512 + hc0 + cr];
    float4 bb2 = *(const float4*)&bsum[2 * 512 + hc0 + cr];
    float4 bb3 = *(const float4*)&bsum[3 * 512 + hc0 + cr];

    float cst[4] = {0.f, 0.f, 0.f, 0.f};

    for (int t = 0; t < T_; ++t) {
      f32x4 a0 = {}, a1 = {}, a2 = {}, a3 = {};
      // ---- gates_x = xs[t] @ W_ih^T : independent of h, issued pre-poll ----
      {
        const short* Ax = xs + ((size_t)t * B_ + brow) * 512 + ko;
#pragma unroll
        for (int kk = 0; kk < 512; kk += 32) {
          bf16x8 xb = *(const bf16x8*)(Ax + kk);
          bf16x8 w0 = lds_ld16B(WB,      lr, kk + ko);
          bf16x8 w1 = lds_ld16B(WB, 16 + lr, kk + ko);
          bf16x8 w2 = lds_ld16B(WB, 32 + lr, kk + ko);
          bf16x8 w3 = lds_ld16B(WB, 48 + lr, kk + ko);
          a0 = mfma16(w0, xb, a0);
          a1 = mfma16(w1, xb, a1);
          a2 = mfma16(w2, xb, a2);
          a3 = mfma16(w3, xb, a3);
        }
      }
      if (t > 0) {
        // ---- wait for peers' h[t-1], then accumulate h-part ----
        const int* fp = gflags + (lane & 31);
        for (;;) {
          int fl = __hip_atomic_load(fp, __ATOMIC_RELAXED, __HIP_MEMORY_SCOPE_AGENT);
          if (__all(fl >= t)) break;
        }
        asm volatile("" ::: "memory");
        const short* Ap = hs + (size_t)(t - 1) * (B_ * H_) + brow * 512 + ko;
#pragma unroll
        for (int kk = 0; kk < 512; kk += 32) {
          bf16x8 hb = *(const bf16x8*)(Ap + kk);
          bf16x8 w0 = lds_ld16B(Wlds,      lr, kk + ko);
          bf16x8 w1 = lds_ld16B(Wlds, 16 + lr, kk + ko);
          bf16x8 w2 = lds_ld16B(Wlds, 32 + lr, kk + ko);
          bf16x8 w3 = lds_ld16B(Wlds, 48 + lr, kk + ko);
          a0 = mfma16(w0, hb, a0);
          a1 = mfma16(w1, hb, a1);
          a2 = mfma16(w2, hb, a2);
          a3 = mfma16(w3, hb, a3);
        }
      }
      // ---- pointwise LSTM cell, fully in-register ----
      unsigned long long hpack = 0;
#pragma unroll
      for (int j = 0; j < 4; ++j) {
        float iv = fsigm(a0[j] + ((const float*)&bb0)[j]);
        float fv = fsigm(a1[j] + ((const float*)&bb1)[j]);
        float gv = ftanh(a2[j] + ((const float*)&bb2)[j]);
        float ov = fsigm(a3[j] + ((const float*)&bb3)[j]);
        float cv = fv * cst[j] + iv * gv;
        cst[j] = cv;
        float hv = ov * ftanh(cv);
        hpack |= (unsigned long long)(unsigned short)f2bf(hv) << (16 * j);
      }
      __hip_atomic_store(
          (unsigned long long*)(hs + (size_t)t * (B_ * H_) + bat * 512 + hc0 + cr),
          hpack, __ATOMIC_RELAXED, __HIP_MEMORY_SCOPE_AGENT);
      // drain own h-store (the ONLY vmem serialization in wave0's loop),
      // then hand the signal to wave 1 via LDS mailbox
      asm volatile("s_waitcnt vmcnt(0)" ::: "memory");
      if (lane == 0)
        __hip_atomic_store(&hmail, t + 1, __ATOMIC_RELAXED,
                           __HIP_MEMORY_SCOPE_WORKGROUP);
    }
  } else {
    // ================= FC consumer role (n-major, fc_W cast into LDS) ======
    const int fblk = blockIdx.x - NLSTM;   // 0..156
    const int n0   = fblk * 64;            // this block's 64 output cols
    const int lane = tid & 63;
    const int wv   = tid >> 6;
    const int lr   = lane & 15;
    const int ko   = (lane >> 4) << 3;

    if (tid == 0)
      __hip_atomic_store(&tready, 0, __ATOMIC_RELAXED, __HIP_MEMORY_SCOPE_WORKGROUP);

    for (int i = tid * 8; i < 64 * 512; i += 256 * 8) {
      int gc = i >> 9;
      int k  = i & 511;
      int nr = n0 + gc; if (nr >= V_) nr = V_ - 1;
      bf16x8 v = cast8(fcWF + (size_t)nr * 512 + k);
      int byte = (i * 2) ^ ((gc & 7) << 4);
      *(bf16x8*)((char*)Wlds + byte) = v;
    }
    __syncthreads();   // covers tready init + Wlds staging

    const int cr = (lane >> 4) * 4, cc = lane & 15;
    const int colw = n0 + wv * 16 + cc;
    const bool wok = colw < V_;
    const float bias = wok ? fcbias[colw] : 0.f;

    for (int t = 0; t < T_; ++t) {
      if (wv == 0) {
        // single poller wave reads ONE word: cnt[t] == 64
        for (;;) {
          int c = __hip_atomic_load(cnt + t, __ATOMIC_RELAXED,
                                    __HIP_MEMORY_SCOPE_AGENT);
          if (c >= NLSTM) break;
          __builtin_amdgcn_s_sleep(32);
        }
        __hip_atomic_store(&tready, t + 1, __ATOMIC_RELAXED,
                           __HIP_MEMORY_SCOPE_WORKGROUP);
      } else {
        while (__hip_atomic_load(&tready, __ATOMIC_RELAXED,
                                 __HIP_MEMORY_SCOPE_WORKGROUP) < t + 1)
          __builtin_amdgcn_s_sleep(2);
      }
      asm volatile("" ::: "memory");
      const short* Ap = hs + (size_t)t * (B_ * H_) + lr * 512 + ko;
      f32x4 acc0 = {}, acc1 = {};
#pragma unroll
      for (int k = 0; k < 512; k += 32) {
        bf16x8 a0 = *(const bf16x8*)(Ap + k);
        bf16x8 a1 = *(const bf16x8*)(Ap + 16 * 512 + k);
        bf16x8 b  = lds_ld16B(Wlds, wv * 16 + lr, k + ko);
        acc0 = mfma16(a0, b, acc0);
        acc1 = mfma16(a1, b, acc1);
      }
      if (wok) {
#pragma unroll
        for (int j = 0; j < 4; ++j) {
          out[(size_t)(cr + j) * (T_ * V_) + t * V_ + colw]      = acc0[j] + bias;
          out[(size_t)(16 + cr + j) * (T_ * V_) + t * V_ + colw] = acc1[j] + bias;
        }
      }
    }
  }
}

// ---------------- launch ----------------

extern "C" void kernel_launch(void* const* d_in, const int* in_sizes, int n_in,
                              void* d_out, int out_size, void* d_ws, size_t ws_size,
                              hipStream_t stream) {
  const float* features = (const float*)d_in[0];
  const int*   captions = (const int*)d_in[1];
  const float* embed    = (const float*)d_in[3];
  const float* W_ih     = (const float*)d_in[4];
  const float* W_hh     = (const float*)d_in[5];
  const float* b_ih     = (const float*)d_in[6];
  const float* b_hh     = (const float*)d_in[7];
  const float* fc_W     = (const float*)d_in[8];
  const float* fc_b     = (const float*)d_in[9];
  float* out = (float*)d_out;

  char* ws = (char*)d_ws;
  size_t off = 0;
  auto alloc = [&](size_t bytes) -> void* {
    off = (off + 255) & ~(size_t)255;
    void* p = ws + off;
    off += bytes;
    return p;
  };
  int*      flags = (int*)  alloc(4096);   // [0..63] flags, [256..319] cnt
  float*    bsum  = (float*)alloc((size_t)G4 * 4);
  short*    xs    = (short*)alloc((size_t)T_ * B_ * E_ * 2);
  short*    hs    = (short*)alloc((size_t)T_ * B_ * H_ * 2);

  (void)hipMemsetAsync(flags, 0, 4096, stream);
  prep_kernel<<<1024, 256, 0, stream>>>(b_ih, b_hh, features, captions, embed,
                                        bsum, xs);
  fused_kernel<<<NTOT, 256, 0, stream>>>(W_hh, W_ih, bsum, xs, hs, flags,
                                         fc_W, fc_b, out);
}